// Round 1
// baseline (218.745 us; speedup 1.0000x reference)
//
#include <hip/hip_runtime.h>
#include <hip/hip_bf16.h>

#define B_ 2
#define H_ 16
#define HKV_ 4
#define S_ 4096
#define D_ 64
#define BN_ 64
#define NB_ 64
#define BPQ_ 6
#define SCALE_ 0.125f
#define LDK 72  // padded LDS row stride (bf16 elems): 144B rows -> 16B aligned, 2-way max conflicts

typedef short bf16x8 __attribute__((ext_vector_type(8)));
typedef short bf16x4v __attribute__((ext_vector_type(4)));
typedef float f32x4 __attribute__((ext_vector_type(4)));

static __device__ __forceinline__ short f2bf(float f) {
    unsigned u = __builtin_bit_cast(unsigned, f);
    unsigned r = u + 0x7FFFu + ((u >> 16) & 1u);   // RNE (inputs are finite normals)
    return (short)(r >> 16);
}

__global__ __launch_bounds__(256) void sparse_attn_kernel(
    const float* __restrict__ q,
    const float* __restrict__ k,
    const float* __restrict__ v,
    const int* __restrict__ seg,
    const int* __restrict__ bidx,
    const float* __restrict__ slopes,
    float* __restrict__ out)
{
    __shared__ short kc[BN_][LDK];      // K chunk, row-major [key][d]
    __shared__ short vt[D_][LDK];       // V chunk, transposed [d][key]
    __shared__ short pl[4][16][LDK];    // per-wave P tile [wave][m][key]

    const int qb   = blockIdx.x;        // query block 0..63
    const int bh   = blockIdx.y;        // 0..31
    const int b    = bh / H_;
    const int h    = bh % H_;
    const int hkv  = h / (H_ / HKV_);
    const int tid  = threadIdx.x;
    const int wave = tid >> 6;
    const int lane = tid & 63;
    const int l16  = lane & 15;
    const int lhi  = lane >> 4;         // 0..3

    const float slope = slopes[h];
    const int   qseg  = seg[b * S_ + qb * BN_];

    // ---- Q fragments (kept in registers; reused across all chunks) ----
    // A-frag layout: row = lane&15, k = (lane>>4)*8 + i  (K=32 per mfma step)
    const int qrow = qb * BN_ + wave * 16 + l16;
    const float* qp = q + (((size_t)(b * H_ + h)) * S_ + qrow) * D_;
    bf16x8 qf[2];
#pragma unroll
    for (int kk = 0; kk < 2; ++kk)
#pragma unroll
        for (int i = 0; i < 8; ++i)
            qf[kk][i] = f2bf(qp[kk * 32 + lhi * 8 + i]);

    f32x4 oacc[4] = {};                 // 4 d-tiles of 16; C/D row = lhi*4+r, col = l16
    float mrun[4], lrun[4];
#pragma unroll
    for (int r = 0; r < 4; ++r) { mrun[r] = -1e30f; lrun[r] = 0.f; }

    const float* kb_ptr = k + ((size_t)(b * HKV_ + hkv)) * S_ * D_;
    const float* vb_ptr = v + ((size_t)(b * HKV_ + hkv)) * S_ * D_;

    const int nch = (qb == 0) ? NB_ : (1 + BPQ_);
    for (int c = 0; c < nch; ++c) {
        int kb;
        if (qb == 0) {
            kb = c * BN_;
        } else if (c == 0) {
            kb = 0;                                  // global keys 0..63
        } else {
            int bi = bidx[qb * BPQ_ + (c - 1)];
            if (bi < 0) continue;                    // block-uniform
            kb = bi * BN_;
        }
        const int kseg = seg[b * S_ + kb];
        if (!(qseg >= 0 && kseg == qseg)) continue;  // block-uniform (chunks are segment-uniform)

        __syncthreads();                             // protect kc/vt from prior readers
        // ---- stage K (row-major) and V (transposed) as bf16 ----
        {
            const float4* ks = (const float4*)(kb_ptr + (size_t)kb * D_);
            const float4* vs = (const float4*)(vb_ptr + (size_t)kb * D_);
#pragma unroll
            for (int it = 0; it < 4; ++it) {
                int idx = tid + it * 256;            // float4 index 0..1023
                int key = idx >> 4;
                int d0  = (idx & 15) * 4;
                float4 kvv = ks[idx];
                bf16x4v k4 = { f2bf(kvv.x), f2bf(kvv.y), f2bf(kvv.z), f2bf(kvv.w) };
                *(bf16x4v*)&kc[key][d0] = k4;
                float4 vv = vs[idx];
                vt[d0 + 0][key] = f2bf(vv.x);
                vt[d0 + 1][key] = f2bf(vv.y);
                vt[d0 + 2][key] = f2bf(vv.z);
                vt[d0 + 3][key] = f2bf(vv.w);
            }
        }
        __syncthreads();

        // ---- QK^T: 16x64 scores per wave ----
        f32x4 sacc[4];
#pragma unroll
        for (int nt = 0; nt < 4; ++nt) {
            f32x4 s = {};
#pragma unroll
            for (int kk = 0; kk < 2; ++kk) {
                bf16x8 kf_ = *(const bf16x8*)&kc[nt * 16 + l16][kk * 32 + lhi * 8];
                s = __builtin_amdgcn_mfma_f32_16x16x32_bf16(qf[kk], kf_, s, 0, 0, 0);
            }
            sacc[nt] = s;
        }

        // ---- scale + alibi + online softmax (rows m = lhi*4+r, col = nt*16+l16) ----
        float pv_[4][4];                 // [nt][r]
#pragma unroll
        for (int r = 0; r < 4; ++r) {
            const int m = lhi * 4 + r;
            const float qpos = (float)(qb * BN_ + wave * 16 + m);
            float mx = -1e30f;
#pragma unroll
            for (int nt = 0; nt < 4; ++nt) {
                float kpos = (float)(kb + nt * 16 + l16);
                float sc = sacc[nt][r] * SCALE_ - slope * fabsf(qpos - kpos);
                pv_[nt][r] = sc;
                mx = fmaxf(mx, sc);
            }
            mx = fmaxf(mx, __shfl_xor(mx, 1));
            mx = fmaxf(mx, __shfl_xor(mx, 2));
            mx = fmaxf(mx, __shfl_xor(mx, 4));
            mx = fmaxf(mx, __shfl_xor(mx, 8));
            const float mn = fmaxf(mrun[r], mx);
            float sum = 0.f;
#pragma unroll
            for (int nt = 0; nt < 4; ++nt) {
                float p = __expf(pv_[nt][r] - mn);
                pv_[nt][r] = p;
                sum += p;
            }
            sum += __shfl_xor(sum, 1);
            sum += __shfl_xor(sum, 2);
            sum += __shfl_xor(sum, 4);
            sum += __shfl_xor(sum, 8);
            const float corr = __expf(mrun[r] - mn);   // first chunk: exp(-1e30-mn)=0
            mrun[r] = mn;
            lrun[r] = lrun[r] * corr + sum;
#pragma unroll
            for (int dt = 0; dt < 4; ++dt) oacc[dt][r] *= corr;
        }

        // ---- P -> LDS (bf16), fix C/D -> A fragment layout mismatch ----
#pragma unroll
        for (int r = 0; r < 4; ++r) {
            const int m = lhi * 4 + r;
#pragma unroll
            for (int nt = 0; nt < 4; ++nt)
                pl[wave][m][nt * 16 + l16] = f2bf(pv_[nt][r]);
        }
        __syncthreads();

        // ---- PV: oacc += P * V ----
#pragma unroll
        for (int kk = 0; kk < 2; ++kk) {
            bf16x8 pf = *(const bf16x8*)&pl[wave][l16][kk * 32 + lhi * 8];
#pragma unroll
            for (int dt = 0; dt < 4; ++dt) {
                bf16x8 vf_ = *(const bf16x8*)&vt[dt * 16 + l16][kk * 32 + lhi * 8];
                oacc[dt] = __builtin_amdgcn_mfma_f32_16x16x32_bf16(pf, vf_, oacc[dt], 0, 0, 0);
            }
        }
    }

    // ---- epilogue: normalize + store ----
    float* op = out + (((size_t)(b * H_ + h)) * S_ + qb * BN_ + wave * 16) * D_;
#pragma unroll
    for (int r = 0; r < 4; ++r) {
        const int m = lhi * 4 + r;
        const float inv = 1.0f / (lrun[r] == 0.f ? 1.f : lrun[r]);
#pragma unroll
        for (int dt = 0; dt < 4; ++dt)
            op[(size_t)m * D_ + dt * 16 + l16] = oacc[dt][r] * inv;
    }
}

extern "C" void kernel_launch(void* const* d_in, const int* in_sizes, int n_in,
                              void* d_out, int out_size, void* d_ws, size_t ws_size,
                              hipStream_t stream) {
    const float* q      = (const float*)d_in[0];
    const float* k      = (const float*)d_in[1];
    const float* v      = (const float*)d_in[2];
    const int*   seg    = (const int*)d_in[3];
    const int*   bidx   = (const int*)d_in[4];
    const float* slopes = (const float*)d_in[5];
    float*       out    = (float*)d_out;

    dim3 grid(NB_, B_ * H_);
    sparse_attn_kernel<<<grid, 256, 0, stream>>>(q, k, v, seg, bidx, slopes, out);
}

// Round 2
// 152.592 us; speedup vs baseline: 1.4335x; 1.4335x over previous
//
#include <hip/hip_runtime.h>
#include <hip/hip_bf16.h>

#define B_ 2
#define H_ 16
#define HKV_ 4
#define S_ 4096
#define D_ 64
#define BN_ 64
#define NB_ 64
#define BPQ_ 6
#define SCALE_ 0.125f
#define LDK 72      // padded LDS row stride (bf16 elems)
#define NSPLIT0 4   // qb==0 split factor
#define PART_ 4224  // per-(bh,split) ws floats: 4096 o + 64 m + 64 l

typedef short bf16x8 __attribute__((ext_vector_type(8)));
typedef short bf16x4v __attribute__((ext_vector_type(4)));
typedef float f32x4 __attribute__((ext_vector_type(4)));

static __device__ __forceinline__ short f2bf(float f) {
    unsigned u = __builtin_bit_cast(unsigned, f);
    unsigned r = u + 0x7FFFu + ((u >> 16) & 1u);   // RNE (finite normals)
    return (short)(r >> 16);
}

__global__ __launch_bounds__(256) void sparse_attn_main(
    const float* __restrict__ q,
    const float* __restrict__ k,
    const float* __restrict__ v,
    const int* __restrict__ seg,
    const int* __restrict__ bidx,
    const float* __restrict__ slopes,
    float* __restrict__ out,
    float* __restrict__ ws)
{
    __shared__ short kc[BN_][LDK];      // K chunk, row-major [key][d]
    __shared__ short vt[D_][LDK];       // V chunk, transposed [d][key]
    __shared__ short pl[4][16][LDK];    // per-wave P tile (no cross-wave hazard)
    __shared__ int vlist[17];
    __shared__ int vcount;

    const int qbx  = blockIdx.x;        // 0..NB_+2
    int qb, split;
    if (qbx < NB_) { qb = qbx; split = 0; }
    else           { qb = 0;   split = qbx - (NB_ - 1); }   // 64,65,66 -> 1,2,3
    const bool split_path = (qb == 0);

    const int bh   = blockIdx.y;
    const int b    = bh / H_;
    const int h    = bh % H_;
    const int hkv  = h / (H_ / HKV_);
    const int tid  = threadIdx.x;
    const int wave = tid >> 6;
    const int lane = tid & 63;
    const int l16  = lane & 15;
    const int lhi  = lane >> 4;

    const float slope = slopes[h];
    const int   qseg  = seg[b * S_ + qb * BN_];

    // ---- valid-chunk list (lane-parallel, wave 0) ----
    if (wave == 0) {
        const int n = split_path ? 16 : (1 + BPQ_);
        int cand = -1;
        if (lane < n) {
            if (split_path)       cand = split + 4 * lane;       // strided quarters
            else if (lane == 0)   cand = 0;                      // global block
            else                  cand = bidx[qb * BPQ_ + lane - 1];
        }
        bool ok = false;
        if (cand >= 0) {
            int ks_ = seg[b * S_ + cand * BN_];
            ok = (qseg >= 0) && (ks_ == qseg);
        }
        unsigned long long m = __ballot(ok);
        if (ok) {
            int rank = __popcll(m & ((1ull << lane) - 1ull));
            vlist[rank] = cand;
        }
        if (lane == 0) vcount = (int)__popcll(m);
    }

    // ---- Q fragments (registers, reused across chunks) ----
    const int qrow = qb * BN_ + wave * 16 + l16;
    const float* qp = q + (((size_t)(b * H_ + h)) * S_ + qrow) * D_;
    bf16x8 qf[2];
#pragma unroll
    for (int kk = 0; kk < 2; ++kk)
#pragma unroll
        for (int i = 0; i < 8; ++i)
            qf[kk][i] = f2bf(qp[kk * 32 + lhi * 8 + i]);

    f32x4 oacc[4] = {};
    float mrun[4], lrun[4];
#pragma unroll
    for (int r = 0; r < 4; ++r) { mrun[r] = -1e30f; lrun[r] = 0.f; }

    const float* kb_ptr = k + ((size_t)(b * HKV_ + hkv)) * S_ * D_;
    const float* vb_ptr = v + ((size_t)(b * HKV_ + hkv)) * S_ * D_;

    __syncthreads();
    const int nval = vcount;

    float4 kr0, kr1, kr2, kr3, vr0, vr1, vr2, vr3;
#define ISSUE_LOADS(CBLK) do { \
        const float4* ks_ = (const float4*)(kb_ptr + (size_t)(CBLK) * (BN_ * D_)); \
        const float4* vs_ = (const float4*)(vb_ptr + (size_t)(CBLK) * (BN_ * D_)); \
        kr0 = ks_[tid];       kr1 = ks_[tid + 256]; \
        kr2 = ks_[tid + 512]; kr3 = ks_[tid + 768]; \
        vr0 = vs_[tid];       vr1 = vs_[tid + 256]; \
        vr2 = vs_[tid + 512]; vr3 = vs_[tid + 768]; \
    } while (0)

#define WRITE_STAGE(IT, KR, VR) do { \
        int idx_ = tid + (IT) * 256; \
        int key_ = idx_ >> 4; \
        int d0_  = (idx_ & 15) * 4; \
        bf16x4v k4_ = { f2bf(KR.x), f2bf(KR.y), f2bf(KR.z), f2bf(KR.w) }; \
        *(bf16x4v*)&kc[key_][d0_] = k4_; \
        vt[d0_ + 0][key_] = f2bf(VR.x); \
        vt[d0_ + 1][key_] = f2bf(VR.y); \
        vt[d0_ + 2][key_] = f2bf(VR.z); \
        vt[d0_ + 3][key_] = f2bf(VR.w); \
    } while (0)

    if (nval > 0) ISSUE_LOADS(vlist[0]);

    for (int i = 0; i < nval; ++i) {
        const int kbase = vlist[i] * BN_;

        __syncthreads();                 // prior chunk's LDS readers done
        WRITE_STAGE(0, kr0, vr0);
        WRITE_STAGE(1, kr1, vr1);
        WRITE_STAGE(2, kr2, vr2);
        WRITE_STAGE(3, kr3, vr3);
        if (i + 1 < nval) ISSUE_LOADS(vlist[i + 1]);   // overlap HBM with compute
        __syncthreads();                 // staging visible

        // ---- QK^T: 16x64 per wave ----
        f32x4 sacc[4];
#pragma unroll
        for (int nt = 0; nt < 4; ++nt) {
            f32x4 s = {};
#pragma unroll
            for (int kk = 0; kk < 2; ++kk) {
                bf16x8 kf_ = *(const bf16x8*)&kc[nt * 16 + l16][kk * 32 + lhi * 8];
                s = __builtin_amdgcn_mfma_f32_16x16x32_bf16(qf[kk], kf_, s, 0, 0, 0);
            }
            sacc[nt] = s;
        }

        // ---- online softmax (rows m = lhi*4+r, cols nt*16+l16) ----
        float pv_[4][4];
#pragma unroll
        for (int r = 0; r < 4; ++r) {
            const int m = lhi * 4 + r;
            const float qpos = (float)(qb * BN_ + wave * 16 + m);
            float mx = -1e30f;
#pragma unroll
            for (int nt = 0; nt < 4; ++nt) {
                float kpos = (float)(kbase + nt * 16 + l16);
                float sc = sacc[nt][r] * SCALE_ - slope * fabsf(qpos - kpos);
                pv_[nt][r] = sc;
                mx = fmaxf(mx, sc);
            }
            mx = fmaxf(mx, __shfl_xor(mx, 1));
            mx = fmaxf(mx, __shfl_xor(mx, 2));
            mx = fmaxf(mx, __shfl_xor(mx, 4));
            mx = fmaxf(mx, __shfl_xor(mx, 8));
            const float mn = fmaxf(mrun[r], mx);
            float sum = 0.f;
#pragma unroll
            for (int nt = 0; nt < 4; ++nt) {
                float p = __expf(pv_[nt][r] - mn);
                pv_[nt][r] = p;
                sum += p;
            }
            sum += __shfl_xor(sum, 1);
            sum += __shfl_xor(sum, 2);
            sum += __shfl_xor(sum, 4);
            sum += __shfl_xor(sum, 8);
            const float corr = __expf(mrun[r] - mn);
            mrun[r] = mn;
            lrun[r] = lrun[r] * corr + sum;
#pragma unroll
            for (int dt = 0; dt < 4; ++dt) oacc[dt][r] *= corr;
        }

        // ---- P -> per-wave LDS (C/D -> A layout fix); no barrier needed ----
#pragma unroll
        for (int r = 0; r < 4; ++r) {
            const int m = lhi * 4 + r;
#pragma unroll
            for (int nt = 0; nt < 4; ++nt)
                pl[wave][m][nt * 16 + l16] = f2bf(pv_[nt][r]);
        }

        // ---- PV ----
#pragma unroll
        for (int kk = 0; kk < 2; ++kk) {
            bf16x8 pf = *(const bf16x8*)&pl[wave][l16][kk * 32 + lhi * 8];
#pragma unroll
            for (int dt = 0; dt < 4; ++dt) {
                bf16x8 vf_ = *(const bf16x8*)&vt[dt * 16 + l16][kk * 32 + lhi * 8];
                oacc[dt] = __builtin_amdgcn_mfma_f32_16x16x32_bf16(pf, vf_, oacc[dt], 0, 0, 0);
            }
        }
    }

    // ---- epilogue ----
    if (split_path) {
        float* wsp = ws + (size_t)(bh * NSPLIT0 + split) * PART_;
#pragma unroll
        for (int r = 0; r < 4; ++r) {
            const int m = wave * 16 + lhi * 4 + r;
#pragma unroll
            for (int dt = 0; dt < 4; ++dt)
                wsp[m * D_ + dt * 16 + l16] = oacc[dt][r];   // unnormalized
            if (l16 == 0) {
                wsp[4096 + m] = mrun[r];
                wsp[4160 + m] = lrun[r];
            }
        }
    } else {
        float* op = out + (((size_t)(b * H_ + h)) * S_ + qb * BN_ + wave * 16) * D_;
#pragma unroll
        for (int r = 0; r < 4; ++r) {
            const int m = lhi * 4 + r;
            const float inv = 1.0f / (lrun[r] == 0.f ? 1.f : lrun[r]);
#pragma unroll
            for (int dt = 0; dt < 4; ++dt)
                op[(size_t)m * D_ + dt * 16 + l16] = oacc[dt][r] * inv;
        }
    }
}

__global__ __launch_bounds__(256) void sparse_attn_combine(
    const float* __restrict__ ws,
    float* __restrict__ out)
{
    const int bh  = blockIdx.x;          // 0..31
    const int t   = threadIdx.x;
    const int row = t >> 2;              // 0..63
    const int d0  = (t & 3) * 16;

    const float* base = ws + (size_t)bh * NSPLIT0 * PART_;
    float ms[NSPLIT0], ls[NSPLIT0];
    float M = -1e30f;
#pragma unroll
    for (int s = 0; s < NSPLIT0; ++s) {
        ms[s] = base[s * PART_ + 4096 + row];
        ls[s] = base[s * PART_ + 4160 + row];
        M = fmaxf(M, ms[s]);
    }
    float w[NSPLIT0];
    float L = 0.f;
#pragma unroll
    for (int s = 0; s < NSPLIT0; ++s) {
        w[s] = __expf(ms[s] - M);
        L += w[s] * ls[s];
    }
    const float inv = 1.0f / (L == 0.f ? 1.f : L);

    float* op = out + ((size_t)bh * S_ + row) * D_ + d0;
#pragma unroll
    for (int j = 0; j < 16; ++j) {
        float acc = 0.f;
#pragma unroll
        for (int s = 0; s < NSPLIT0; ++s)
            acc += w[s] * base[s * PART_ + row * D_ + d0 + j];
        op[j] = acc * inv;
    }
}

extern "C" void kernel_launch(void* const* d_in, const int* in_sizes, int n_in,
                              void* d_out, int out_size, void* d_ws, size_t ws_size,
                              hipStream_t stream) {
    const float* q      = (const float*)d_in[0];
    const float* k      = (const float*)d_in[1];
    const float* v      = (const float*)d_in[2];
    const int*   seg    = (const int*)d_in[3];
    const int*   bidx   = (const int*)d_in[4];
    const float* slopes = (const float*)d_in[5];
    float*       out    = (float*)d_out;
    float*       ws     = (float*)d_ws;

    dim3 grid(NB_ + (NSPLIT0 - 1), B_ * H_);
    sparse_attn_main<<<grid, 256, 0, stream>>>(q, k, v, seg, bidx, slopes, out, ws);
    sparse_attn_combine<<<dim3(B_ * H_), 256, 0, stream>>>(ws, out);
}

// Round 4
// 139.451 us; speedup vs baseline: 1.5686x; 1.0942x over previous
//
#include <hip/hip_runtime.h>
#include <hip/hip_bf16.h>

#define B_ 2
#define H_ 16
#define HKV_ 4
#define S_ 4096
#define D_ 64
#define BN_ 64
#define NB_ 64
#define BPQ_ 6
#define QSCALE_LOG2 0.18033688f   // (1/sqrt(64)) * log2(e)
#define LOG2E 1.44269504f
#define LDK 72      // padded LDS row stride (bf16 elems), rows 16B-aligned
#define NSPLIT0 4   // qb==0 split factor
#define PART_ 4224  // per-(bh,split) ws floats: 4096 o + 64 m + 64 l

typedef short bf16x8 __attribute__((ext_vector_type(8)));
typedef short bf16x4v __attribute__((ext_vector_type(4)));
typedef float f32x4 __attribute__((ext_vector_type(4)));
typedef unsigned int u32x4 __attribute__((ext_vector_type(4)));

static __device__ __forceinline__ short f2bf(float f) {
    unsigned u = __builtin_bit_cast(unsigned, f);
    unsigned r = u + 0x7FFFu + ((u >> 16) & 1u);   // RNE (finite normals)
    return (short)(r >> 16);
}

static __device__ __forceinline__ unsigned cvt_pk_bf16(float lo, float hi) {
    unsigned r;
    asm("v_cvt_pk_bf16_f32 %0, %1, %2" : "=v"(r) : "v"(lo), "v"(hi));
    return r;   // low16 = bf16(lo), high16 = bf16(hi)
}

__global__ __launch_bounds__(256) void sparse_attn_main(
    const float* __restrict__ q,
    const float* __restrict__ k,
    const float* __restrict__ v,
    const int* __restrict__ seg,
    const int* __restrict__ bidx,
    const float* __restrict__ slopes,
    float* __restrict__ out,
    float* __restrict__ ws)
{
    __shared__ short kc[BN_][LDK];      // K chunk, [key][d], unswizzled
    __shared__ short vt[D_][LDK];       // V chunk, [d][key ^ 8*((d>>2)&7)]
    __shared__ int vlist[17];
    __shared__ int vcount;

    const int qbx  = blockIdx.x;        // 0..NB_+2
    int qb, split;
    if (qbx < NB_) { qb = qbx; split = 0; }
    else           { qb = 0;   split = qbx - (NB_ - 1); }   // 64,65,66 -> 1,2,3
    const bool split_path = (qb == 0);

    const int bh   = blockIdx.y;
    const int b    = bh / H_;
    const int h    = bh % H_;
    const int hkv  = h / (H_ / HKV_);
    const int tid  = threadIdx.x;
    const int wave = tid >> 6;
    const int lane = tid & 63;
    const int l16  = lane & 15;
    const int lhi  = lane >> 4;         // 0..3

    const float slope2 = slopes[h] * LOG2E;
    const int   qseg   = seg[b * S_ + qb * BN_];

    // ---- valid-chunk list (lane-parallel, wave 0) ----
    if (wave == 0) {
        const int n = split_path ? 16 : (1 + BPQ_);
        int cand = -1;
        if (lane < n) {
            if (split_path)       cand = split + 4 * lane;       // strided quarters
            else if (lane == 0)   cand = 0;                      // global block
            else                  cand = bidx[qb * BPQ_ + lane - 1];
        }
        bool ok = false;
        if (cand >= 0) {
            int ks_ = seg[b * S_ + cand * BN_];
            ok = (qseg >= 0) && (ks_ == qseg);
        }
        unsigned long long m = __ballot(ok);
        if (ok) {
            int rank = __popcll(m & ((1ull << lane) - 1ull));
            vlist[rank] = cand;
        }
        if (lane == 0) vcount = (int)__popcll(m);
    }

    // ---- Q fragment (used as MFMA *B* operand), SCALE*log2e folded in ----
    // B-frag: col = l16 = q-row-in-tile, k-slot (lhi,i) = d = 32kk+8lhi+i
    const int qrow = qb * BN_ + wave * 16 + l16;
    const float qpos = (float)qrow;
    const float* qp = q + (((size_t)(b * H_ + h)) * S_ + qrow) * D_;
    bf16x8 qf[2];
#pragma unroll
    for (int kk = 0; kk < 2; ++kk)
#pragma unroll
        for (int i = 0; i < 8; ++i)
            qf[kk][i] = f2bf(qp[kk * 32 + lhi * 8 + i] * QSCALE_LOG2);

    // O^T accumulators: oacc[dt] reg r -> row d = 16dt+4lhi+r, col q = l16
    f32x4 oacc[4] = {};
    float mrun = -1e30f, lrun = 0.f;    // per-lane scalars (q = l16), log2 domain

    const float* kb_ptr = k + ((size_t)(b * HKV_ + hkv)) * S_ * D_;
    const float* vb_ptr = v + ((size_t)(b * HKV_ + hkv)) * S_ * D_;

    __syncthreads();
    const int nval = vcount;

    float4 kr0, kr1, kr2, kr3, vr0, vr1, vr2, vr3;
#define ISSUE_LOADS(CBLK) do { \
        const float4* ks_ = (const float4*)(kb_ptr + (size_t)(CBLK) * (BN_ * D_)); \
        const float4* vs_ = (const float4*)(vb_ptr + (size_t)(CBLK) * (BN_ * D_)); \
        kr0 = ks_[tid];       kr1 = ks_[tid + 256]; \
        kr2 = ks_[tid + 512]; kr3 = ks_[tid + 768]; \
        vr0 = vs_[tid];       vr1 = vs_[tid + 256]; \
        vr2 = vs_[tid + 512]; vr3 = vs_[tid + 768]; \
    } while (0)

    // thread holds one key (4 d-values). kc: b64 write. vt: 4 scalar writes,
    // key index XOR-swizzled by 8*((d>>2)&7) (= 8*(l16&7) since d0 = 4*l16).
#define WRITE_STAGE(IT, KR, VR) do { \
        int idx_ = tid + (IT) * 256; \
        int key_ = idx_ >> 4; \
        int d0_  = (idx_ & 15) * 4; \
        bf16x4v k4_ = { f2bf(KR.x), f2bf(KR.y), f2bf(KR.z), f2bf(KR.w) }; \
        *(bf16x4v*)&kc[key_][d0_] = k4_; \
        int sw_ = key_ ^ (((d0_ >> 2) & 7) << 3); \
        vt[d0_ + 0][sw_] = f2bf(VR.x); \
        vt[d0_ + 1][sw_] = f2bf(VR.y); \
        vt[d0_ + 2][sw_] = f2bf(VR.z); \
        vt[d0_ + 3][sw_] = f2bf(VR.w); \
    } while (0)

    if (nval > 0) ISSUE_LOADS(vlist[0]);

    for (int i = 0; i < nval; ++i) {
        const int kbase = vlist[i] * BN_;

        __syncthreads();                 // prior chunk's LDS readers done
        WRITE_STAGE(0, kr0, vr0);
        WRITE_STAGE(1, kr1, vr1);
        WRITE_STAGE(2, kr2, vr2);
        WRITE_STAGE(3, kr3, vr3);
        if (i + 1 < nval) ISSUE_LOADS(vlist[i + 1]);   // overlap HBM with compute
        __syncthreads();                 // staging visible

        // ---- swapped QK^T: S^T = K * Q^T per 16-key tile ----
        // sacc[nt] reg r: S^T[key = 16nt+4lhi+r][q = l16]
        f32x4 sacc[4];
#pragma unroll
        for (int nt = 0; nt < 4; ++nt) {
            f32x4 s = {};
#pragma unroll
            for (int kk = 0; kk < 2; ++kk) {
                bf16x8 kf_ = *(const bf16x8*)&kc[nt * 16 + l16][kk * 32 + lhi * 8];
                s = __builtin_amdgcn_mfma_f32_16x16x32_bf16(kf_, qf[kk], s, 0, 0, 0);
            }
            sacc[nt] = s;
        }

        // ---- online softmax, log2 domain, per-lane scalars (q = l16) ----
        float p_[4][4];
        float mx = -1e30f;
#pragma unroll
        for (int nt = 0; nt < 4; ++nt)
#pragma unroll
            for (int r = 0; r < 4; ++r) {
                float kpos = (float)(kbase + nt * 16 + lhi * 4 + r);
                float sc = sacc[nt][r] - slope2 * fabsf(qpos - kpos);
                p_[nt][r] = sc;
                mx = fmaxf(mx, sc);
            }
        mx = fmaxf(mx, __shfl_xor(mx, 16));
        mx = fmaxf(mx, __shfl_xor(mx, 32));
        const float mn = fmaxf(mrun, mx);
        float sum = 0.f;
#pragma unroll
        for (int nt = 0; nt < 4; ++nt)
#pragma unroll
            for (int r = 0; r < 4; ++r) {
                float p = exp2f(p_[nt][r] - mn);
                p_[nt][r] = p;
                sum += p;
            }
        sum += __shfl_xor(sum, 16);
        sum += __shfl_xor(sum, 32);
        const float corr = exp2f(mrun - mn);   // first chunk: 0
        mrun = mn;
        lrun = lrun * corr + sum;
#pragma unroll
        for (int dt = 0; dt < 4; ++dt) oacc[dt] *= corr;

        // ---- P^T -> bf16 pairs, fully in-lane (k-slot permutation) ----
        unsigned pk_[4][2];
#pragma unroll
        for (int nt = 0; nt < 4; ++nt) {
            pk_[nt][0] = cvt_pk_bf16(p_[nt][0], p_[nt][1]);
            pk_[nt][1] = cvt_pk_bf16(p_[nt][2], p_[nt][3]);
        }

        // ---- PV: O^T += V^T * P^T, k-slot (lhi,i) = key 32kk+16(i>>2)+4lhi+(i&3) ----
#pragma unroll
        for (int kk = 0; kk < 2; ++kk) {
            u32x4 pw = { pk_[2 * kk][0], pk_[2 * kk][1],
                         pk_[2 * kk + 1][0], pk_[2 * kk + 1][1] };
            bf16x8 pf = __builtin_bit_cast(bf16x8, pw);
#pragma unroll
            for (int dt = 0; dt < 4; ++dt) {
                const short* vrow = &vt[dt * 16 + l16][0];
                const int sv8 = ((4 * dt + (l16 >> 2)) & 7) << 3;
                bf16x4v lo = *(const bf16x4v*)&vrow[(kk * 32 + 4 * lhi) ^ sv8];
                bf16x4v hi = *(const bf16x4v*)&vrow[(kk * 32 + 16 + 4 * lhi) ^ sv8];
                bf16x8 vf = __builtin_shufflevector(lo, hi, 0, 1, 2, 3, 4, 5, 6, 7);
                oacc[dt] = __builtin_amdgcn_mfma_f32_16x16x32_bf16(vf, pf, oacc[dt], 0, 0, 0);
            }
        }
    }

    // ---- epilogue: lane holds O^T[16dt+4lhi+r][q=l16] ----
    if (split_path) {
        float* wsp = ws + (size_t)(bh * NSPLIT0 + split) * PART_;
        const int m = wave * 16 + l16;
#pragma unroll
        for (int dt = 0; dt < 4; ++dt) {
            float4 o4 = { oacc[dt][0], oacc[dt][1], oacc[dt][2], oacc[dt][3] };
            *(float4*)&wsp[m * D_ + dt * 16 + 4 * lhi] = o4;   // unnormalized
        }
        if (lhi == 0) {
            wsp[4096 + m] = mrun;   // log2 domain
            wsp[4160 + m] = lrun;
        }
    } else {
        const float inv = 1.0f / (lrun == 0.f ? 1.f : lrun);
        float* op = out + ((size_t)bh * S_ + qrow) * D_;
#pragma unroll
        for (int dt = 0; dt < 4; ++dt) {
            float4 o4 = { oacc[dt][0] * inv, oacc[dt][1] * inv,
                          oacc[dt][2] * inv, oacc[dt][3] * inv };
            *(float4*)&op[dt * 16 + 4 * lhi] = o4;
        }
    }
}

__global__ __launch_bounds__(256) void sparse_attn_combine(
    const float* __restrict__ ws,
    float* __restrict__ out)
{
    const int bh  = blockIdx.x;          // 0..31
    const int t   = threadIdx.x;
    const int row = t >> 2;              // 0..63
    const int d0  = (t & 3) * 16;

    const float* base = ws + (size_t)bh * NSPLIT0 * PART_;
    float ms[NSPLIT0], ls[NSPLIT0];
    float M = -1e30f;
#pragma unroll
    for (int s = 0; s < NSPLIT0; ++s) {
        ms[s] = base[s * PART_ + 4096 + row];
        ls[s] = base[s * PART_ + 4160 + row];
        M = fmaxf(M, ms[s]);
    }
    float w[NSPLIT0];
    float L = 0.f;
#pragma unroll
    for (int s = 0; s < NSPLIT0; ++s) {
        w[s] = exp2f(ms[s] - M);        // log2 domain
        L += w[s] * ls[s];
    }
    const float inv = 1.0f / (L == 0.f ? 1.f : L);

    float* op = out + ((size_t)bh * S_ + row) * D_ + d0;
#pragma unroll
    for (int j = 0; j < 16; ++j) {
        float acc = 0.f;
#pragma unroll
        for (int s = 0; s < NSPLIT0; ++s)
            acc += w[s] * base[s * PART_ + row * D_ + d0 + j];
        op[j] = acc * inv;
    }
}

extern "C" void kernel_launch(void* const* d_in, const int* in_sizes, int n_in,
                              void* d_out, int out_size, void* d_ws, size_t ws_size,
                              hipStream_t stream) {
    const float* q      = (const float*)d_in[0];
    const float* k      = (const float*)d_in[1];
    const float* v      = (const float*)d_in[2];
    const int*   seg    = (const int*)d_in[3];
    const int*   bidx   = (const int*)d_in[4];
    const float* slopes = (const float*)d_in[5];
    float*       out    = (float*)d_out;
    float*       ws     = (float*)d_ws;

    dim3 grid(NB_ + (NSPLIT0 - 1), B_ * H_);
    sparse_attn_main<<<grid, 256, 0, stream>>>(q, k, v, seg, bidx, slopes, out, ws);
    sparse_attn_combine<<<dim3(B_ * H_), 256, 0, stream>>>(ws, out);
}